// Round 4
// baseline (9538.132 us; speedup 1.0000x reference)
//
#include <hip/hip_runtime.h>
#include <hip/hip_fp16.h>
#include <stdint.h>

// LSTM policy rollout, fully weight-resident.
// 512 blocks x 256 threads (2 blocks/CU, 2 waves/SIMD, 256-VGPR cap).
// Block owns 8 h-rows = 24 gate rows; each of 4 waves owns 6 rows:
//   4 rows in VGPRs (128 regs f16x2) + 2 rows in LDS (16 KB).
// Per-step global traffic = h exchange (24 KB) + 512 flag words.

#define HID    4096
#define CTX    1024
#define NSTEPS 256
#define NBLK   512
#define TPB    256
#define WAVES  4
#define HROWS  8           // h rows per block
#define GROWS  24          // gate rows per block
#define RPW    6           // rows per wave (4 VGPR + 2 LDS)
#define NCH    8           // column chunks of 512

typedef _Float16 h2 __attribute__((ext_vector_type(2)));

__device__ __forceinline__ float fdot2f(uint32_t a, uint32_t b, float c) {
#if __has_builtin(__builtin_amdgcn_fdot2)
  return __builtin_amdgcn_fdot2(__builtin_bit_cast(h2, a),
                                __builtin_bit_cast(h2, b), c, false);
#else
  h2 x = __builtin_bit_cast(h2, a), y = __builtin_bit_cast(h2, b);
  return c + (float)x[0]*(float)y[0] + (float)x[1]*(float)y[1];
#endif
}
__device__ __forceinline__ uint32_t pkf16(float x, float y) {
  h2 v; v[0] = (_Float16)x; v[1] = (_Float16)y;
  return __builtin_bit_cast(uint32_t, v);
}
__device__ __forceinline__ uint4 cvt8(const float* p) {
  return make_uint4(pkf16(p[0],p[1]), pkf16(p[2],p[3]),
                    pkf16(p[4],p[5]), pkf16(p[6],p[7]));
}
__device__ __forceinline__ float dot4(float acc, uint4 wv_, uint4 zz) {
  acc = fdot2f(wv_.x, zz.x, acc); acc = fdot2f(wv_.y, zz.y, acc);
  acc = fdot2f(wv_.z, zz.z, acc); acc = fdot2f(wv_.w, zz.w, acc);
  return acc;
}

__global__ __launch_bounds__(TPB, 2)
void lstm(const float* __restrict__ ctx, const float* __restrict__ u,
          const float* __restrict__ l1w, const float* __restrict__ l1b,
          const float* __restrict__ Wf,  const float* __restrict__ Wfb,
          const float* __restrict__ Wi,  const float* __restrict__ Wib,
          const float* __restrict__ Wc,  const float* __restrict__ Wcb,
          const float* __restrict__ Wow, const float* __restrict__ Wob,
          float* __restrict__ hf0, float* __restrict__ hf1,
          uint32_t* __restrict__ hh0, uint32_t* __restrict__ hh1,
          uint32_t* __restrict__ flags, float* __restrict__ out)
{
  __shared__ uint4 wlds[2*WAVES][HID/8];  // 2 LDS rows per wave, 64 KB
  __shared__ uint4 zsh4[HID/8];           // z packed f16x2, 8 KB
  __shared__ float red[WAVES];
  __shared__ float pre[GROWS];
  __shared__ float cst[HROWS];
  __shared__ float bias[GROWS];
  __shared__ float wx[GROWS];             // column-4096 (x) weight per row
  __shared__ float x0sh;

  const int tid  = threadIdx.x;
  const int b    = blockIdx.x;
  const int wv   = tid >> 6;
  const int lane = tid & 63;

  uint32_t* z32 = (uint32_t*)zsh4;
  for (int i = tid; i < HID/2; i += TPB) z32[i] = 0u;
  if (tid < HROWS) cst[tid] = 0.f;
  if (tid < GROWS) {
    int g = tid / HROWS, j = tid % HROWS;
    const float* bw = (g==0 ? Wfb : (g==1 ? Wib : Wcb));
    const float* gw = (g==0 ? Wf  : (g==1 ? Wi  : Wc ));
    bias[tid] = bw[b*HROWS + j];
    wx[tid]   = gw[(size_t)(b*HROWS + j)*4097 + 4096];
  }

  // o-gate weights resident (step-invariant), f32
  float wow[16];
  #pragma unroll
  for (int k = 0; k < 16; ++k) wow[k] = Wow[tid + k*TPB];
  const float woxw = Wow[HID];
  const float wob0 = Wob[0];

  // load + convert this wave's 6 gate rows: 4 -> VGPRs, 2 -> LDS
  uint4 wrA0[NCH], wrA1[NCH], wrA2[NCH], wrA3[NCH];
  {
    const float* rp[RPW];
    #pragma unroll
    for (int r = 0; r < RPW; ++r) {
      const int fl = wv*RPW + r;
      const int g = fl / HROWS, j = fl % HROWS;
      rp[r] = (g==0 ? Wf : (g==1 ? Wi : Wc)) + (size_t)(b*HROWS + j)*4097;
    }
    #pragma unroll
    for (int c = 0; c < NCH; ++c) {
      const int col = c*512 + lane*8;
      wrA0[c] = cvt8(rp[0] + col);
      wrA1[c] = cvt8(rp[1] + col);
      wrA2[c] = cvt8(rp[2] + col);
      wrA3[c] = cvt8(rp[3] + col);
      wlds[2*wv+0][c*64 + lane] = cvt8(rp[4] + col);
      wlds[2*wv+1][c*64 + lane] = cvt8(rp[5] + col);
    }
  }

  // x0 = l1_w . context + l1_b (identical in every block)
  {
    float p = 0.f;
    #pragma unroll
    for (int k = 0; k < CTX/TPB; ++k)
      p = fmaf(l1w[tid + k*TPB], ctx[tid + k*TPB], p);
    #pragma unroll
    for (int off = 32; off; off >>= 1) p += __shfl_down(p, off, 64);
    __syncthreads();                 // covers zsh4 zero-init + wlds + cst
    if (lane == 0) red[wv] = p;
    __syncthreads();
    if (tid == 0) x0sh = ((red[0]+red[1])+red[2])+red[3] + l1b[0];
    __syncthreads();
  }
  float xcur = x0sh;
  float logp = 0.f;
  float hreg[16];
  #pragma unroll
  for (int k = 0; k < 16; ++k) hreg[k] = 0.f;

  for (int t = 0; t < NSTEPS; ++t) {
    // ---- o gate (f32, bit-identical across blocks) ----
    float p = 0.f;
    if (t > 0) {
      #pragma unroll
      for (int k = 0; k < 16; ++k) p = fmaf(wow[k], hreg[k], p);
    }
    #pragma unroll
    for (int off = 32; off; off >>= 1) p += __shfl_down(p, off, 64);
    if (lane == 0) red[wv] = p;
    __syncthreads();
    const float osum = ((red[0]+red[1])+red[2])+red[3];
    const float opre = osum + woxw*xcur + wob0;
    const float o = 1.f / (1.f + expf(-opre));
    const float s = (u[t] < o) ? 1.f : 0.f;

    // ---- f/i/c gate dots from resident weights ----
    float a0=0.f,a1=0.f,a2=0.f,a3=0.f,a4=0.f,a5=0.f;
    #pragma unroll
    for (int c = 0; c < NCH; ++c) {
      const uint4 zz = zsh4[c*64 + lane];
      const uint4 w4 = wlds[2*wv+0][c*64 + lane];
      const uint4 w5 = wlds[2*wv+1][c*64 + lane];
      a0 = dot4(a0, wrA0[c], zz);
      a1 = dot4(a1, wrA1[c], zz);
      a2 = dot4(a2, wrA2[c], zz);
      a3 = dot4(a3, wrA3[c], zz);
      a4 = dot4(a4, w4, zz);
      a5 = dot4(a5, w5, zz);
    }
    #pragma unroll
    for (int off = 32; off; off >>= 1) {
      a0 += __shfl_down(a0, off, 64); a1 += __shfl_down(a1, off, 64);
      a2 += __shfl_down(a2, off, 64); a3 += __shfl_down(a3, off, 64);
      a4 += __shfl_down(a4, off, 64); a5 += __shfl_down(a5, off, 64);
    }
    if (lane == 0) {
      const int fl = wv*RPW;
      pre[fl+0] = a0 + wx[fl+0]*xcur + bias[fl+0];
      pre[fl+1] = a1 + wx[fl+1]*xcur + bias[fl+1];
      pre[fl+2] = a2 + wx[fl+2]*xcur + bias[fl+2];
      pre[fl+3] = a3 + wx[fl+3]*xcur + bias[fl+3];
      pre[fl+4] = a4 + wx[fl+4]*xcur + bias[fl+4];
      pre[fl+5] = a5 + wx[fl+5]*xcur + bias[fl+5];
    }
    __syncthreads();

    // ---- h update: all stores from wave 0 so tid0's fence covers them ----
    float* hwF = (t & 1) ? hf1 : hf0;
    uint32_t* hwH = (t & 1) ? hh1 : hh0;
    float hv = 0.f;
    if (tid < HROWS) {
      const float ff = 1.f / (1.f + expf(-pre[tid]));
      const float ii = 1.f / (1.f + expf(-pre[HROWS+tid]));
      const float cc = tanhf(pre[2*HROWS+tid]);
      const float cn = ff*cst[tid] + ii*cc;
      cst[tid] = cn;
      hv = o * tanhf(cn);
      hwF[b*HROWS + tid] = hv;
    }
    if (tid < 64) {
      const float he = __shfl(hv, 2*(tid&7),   64);
      const float ho = __shfl(hv, 2*(tid&7)+1, 64);
      if (tid < 4) hwH[b*4 + tid] = pkf16(he, ho);
    }
    if (b == 0 && tid == 0) {
      logp += (s != 0.f) ? logf(o) : logf(1.f - o);
      out[t] = s;
    }
    xcur = s;

    if (t + 1 < NSTEPS) {
      // ---- flag barrier: release publish, relaxed poll, one acquire fence ----
      if (tid == 0) {
        __threadfence();   // write back this wave's h stores to coherent point
        __hip_atomic_store(&flags[b], (uint32_t)(t+1), __ATOMIC_RELEASE,
                           __HIP_MEMORY_SCOPE_AGENT);
      }
      {
        const uint32_t tg = (uint32_t)(t+1);
        bool d0 = false, d1 = false;
        while (!(d0 & d1)) {
          if (!d0) d0 = __hip_atomic_load(&flags[tid], __ATOMIC_RELAXED,
                                          __HIP_MEMORY_SCOPE_AGENT) >= tg;
          if (!d1) d1 = __hip_atomic_load(&flags[tid+TPB], __ATOMIC_RELAXED,
                                          __HIP_MEMORY_SCOPE_AGENT) >= tg;
          if (!(d0 & d1)) __builtin_amdgcn_s_sleep(1);
        }
      }
      __syncthreads();
      __builtin_amdgcn_fence(__ATOMIC_ACQUIRE, "agent");

      // ---- gather z(t): f16 to LDS for gate dots, f32 to regs for o-gate ----
      const float*    hrF = (t & 1) ? hf1 : hf0;
      const uint32_t* hr2 = (t & 1) ? hh1 : hh0;
      #pragma unroll
      for (int k = 0; k < 16; ++k) hreg[k] = hrF[tid + k*TPB];
      #pragma unroll
      for (int k = 0; k < 8; ++k) z32[tid + k*TPB] = hr2[tid + k*TPB];
      __syncthreads();
    }
  }
  if (b == 0 && tid == 0) out[NSTEPS] = logp;
}

extern "C" void kernel_launch(void* const* d_in, const int* in_sizes, int n_in,
                              void* d_out, int out_size, void* d_ws, size_t ws_size,
                              hipStream_t stream) {
  const float* ctx = (const float*)d_in[0];
  const float* u   = (const float*)d_in[1];
  const float* l1w = (const float*)d_in[2];
  const float* l1b = (const float*)d_in[3];
  const float* Wf  = (const float*)d_in[4];
  const float* Wfb = (const float*)d_in[5];
  const float* Wi  = (const float*)d_in[6];
  const float* Wib = (const float*)d_in[7];
  const float* Wc  = (const float*)d_in[8];
  const float* Wcb = (const float*)d_in[9];
  const float* Wow = (const float*)d_in[10];
  const float* Wob = (const float*)d_in[11];
  float* out = (float*)d_out;

  char* ws = (char*)d_ws;
  uint32_t* flags = (uint32_t*)ws;                 // 512*4 B (memset 4 KB)
  float*    hf0   = (float*)(ws + 4096);
  float*    hf1   = (float*)(ws + 4096 + HID*4);
  uint32_t* hh0   = (uint32_t*)(ws + 4096 + 2*HID*4);
  uint32_t* hh1   = (uint32_t*)(ws + 4096 + 2*HID*4 + HID*2);

  (void)hipMemsetAsync(flags, 0, 4096, stream);
  lstm<<<NBLK, TPB, 0, stream>>>(ctx,u,l1w,l1b,Wf,Wfb,Wi,Wib,Wc,Wcb,Wow,Wob,
                                 hf0,hf1,hh0,hh1,flags,out);
}